// Round 10
// baseline (178.209 us; speedup 1.0000x reference)
//
#include <hip/hip_runtime.h>

#define SQ   2048
#define HEADS 16
#define HD   64
#define EMB  1024

typedef __attribute__((ext_vector_type(2))) __fp16 h2;
typedef __attribute__((ext_vector_type(4))) __fp16 h4;
typedef __attribute__((ext_vector_type(8))) __fp16 h8;
typedef __attribute__((ext_vector_type(4))) float f4;
typedef unsigned short USH;
typedef unsigned int   UI;

__device__ __forceinline__ UI pkh(float a, float b) {   // pack 2 f16 (RTZ)
    h2 v = __builtin_amdgcn_cvt_pkrtz(a, b);
    return __builtin_bit_cast(UI, v);
}

// async global->LDS, 16B per lane; LDS dest = wave-uniform base + lane*16
__device__ __forceinline__ void glds16(const void* g, void* l) {
    __builtin_amdgcn_global_load_lds(
        (const __attribute__((address_space(1))) unsigned int*)g,
        (__attribute__((address_space(3))) unsigned int*)l, 16, 0, 0);
}

// ---------------------------------------------------------------------------
// Fused Q/K/V per-head projections (y=0,1,2) + Wo fp32->f16 cast (y=3).
// (r9-verified: coalesced LDS-bounced stores; part of the -13us proj+gemm
// win. UNCHANGED in r10.)
// ---------------------------------------------------------------------------
__global__ __launch_bounds__(256) void proj_fused(
    const float* __restrict__ q_in, const float* __restrict__ k_in,
    const float* __restrict__ v_in, const float* __restrict__ Wq,
    const float* __restrict__ Wk,   const float* __restrict__ Wv,
    const float* __restrict__ Wo,
    USH* __restrict__ Qh, USH* __restrict__ Kh, USH* __restrict__ Vt,
    USH* __restrict__ Wob)
{
    int t = threadIdx.x;
    if (blockIdx.y == 3) {
        int i = blockIdx.x * 256 + t;
        for (int j = 0; j < 4; ++j) {
            float4 v = ((const float4*)Wo)[i + j * 65536];
            uint2 pk; pk.x = pkh(v.x, v.y); pk.y = pkh(v.z, v.w);
            *(uint2*)(Wob + ((size_t)i + (size_t)j * 65536) * 4) = pk;
        }
        return;
    }
    const float* X = (blockIdx.y == 0) ? q_in : (blockIdx.y == 1) ? k_in : v_in;
    const float* W = (blockIdx.y == 0) ? Wq   : (blockIdx.y == 1) ? Wk   : Wv;
    float scale    = (blockIdx.y == 0) ? 0.18033688011112043f : 1.0f;

    int bx = (blockIdx.x & 7) * 32 + (blockIdx.x >> 3);

    __shared__ __align__(16) union {
        struct { USH Xl[256][72]; USH Wl[64][72]; } in;   // 46080 B
        USH oqk[16 * 1160];                               // [h][sl(72)][d] 37120 B
        USH ov[16 * 1544];                                // [h][d(24)][sl] 49408 B
    } sm;

    const float4* Xg = (const float4*)(X + (size_t)bx * 16384);
    for (int j = 0; j < 16; ++j) {
        int f = t + j * 256;
        float4 v = Xg[f];
        int row = f >> 4; int col = (f & 15) << 2;
        uint2 pk; pk.x = pkh(v.x, v.y); pk.y = pkh(v.z, v.w);
        *(uint2*)&sm.in.Xl[row][col] = pk;
    }
    const float4* Wg = (const float4*)W;
    for (int j = 0; j < 4; ++j) {
        int f = t + j * 256;
        float4 v = Wg[f];
        int row = f >> 4; int col = (f & 15) << 2;
        uint2 pk; pk.x = pkh(v.x, v.y); pk.y = pkh(v.z, v.w);
        *(uint2*)&sm.in.Wl[row][col] = pk;
    }
    __syncthreads();

    int wv = t >> 6, lane = t & 63, l4 = lane & 15, quad = lane >> 4;

    h8 wf[4][2], xf[4][2];
    for (int et = 0; et < 4; ++et)
        for (int ks = 0; ks < 2; ++ks)
            wf[et][ks] = *(const h8*)&sm.in.Wl[et * 16 + l4][ks * 32 + quad * 8];
    for (int rt = 0; rt < 4; ++rt)
        for (int ks = 0; ks < 2; ++ks)
            xf[rt][ks] = *(const h8*)&sm.in.Xl[wv * 64 + rt * 16 + l4][ks * 32 + quad * 8];

    __syncthreads();   // all waves done reading sm.in before union reuse

    f4 acc[4][4];
    for (int et = 0; et < 4; ++et)
        for (int rt = 0; rt < 4; ++rt) acc[et][rt] = (f4)(0.0f);
    for (int et = 0; et < 4; ++et)
        for (int rt = 0; rt < 4; ++rt)
            for (int ks = 0; ks < 2; ++ks)
                acc[et][rt] = __builtin_amdgcn_mfma_f32_16x16x32_f16(
                    wf[et][ks], xf[rt][ks], acc[et][rt], 0, 0, 0);

    int ns0 = bx * 16;
    int n = ns0 >> 11, s0 = ns0 & 2047;   // block never crosses n (2048%16==0)

    if (blockIdx.y == 2) {
        // LDS layout [h][d][sl]: h-stride 1544, d-stride 24 (48B, 16B-aligned)
        for (int et = 0; et < 4; ++et)
            for (int j = 0; j < 4; ++j) {
                int e = et * 16 + quad * 4 + j;
                uint2 pk;
                pk.x = pkh(acc[et][0][j], acc[et][1][j]);
                pk.y = pkh(acc[et][2][j], acc[et][3][j]);
                *(uint2*)&sm.ov[l4 * 1544 + e * 24 + wv * 4] = pk;
            }
        __syncthreads();
        // rows (h,d): 1024 rows x 32B, 4 per thread, lane-consecutive d
        for (int k = 0; k < 4; ++k) {
            int g = k * 256 + t; int h = g >> 6, d = g & 63;
            const USH* src = &sm.ov[h * 1544 + d * 24];
            uint4 v0 = *(const uint4*)src;
            uint4 v1 = *(const uint4*)(src + 8);
            USH* dst = Vt + (((size_t)(n * HEADS + h) * HD + d) * SQ + s0);
            *(uint4*)dst = v0;
            *(uint4*)(dst + 8) = v1;
        }
    } else {
        USH* Out = (blockIdx.y == 0) ? Qh : Kh;
        // LDS layout [h][sl][d]: h-stride 1160, sl-stride 72 (144B, 16B-aligned)
        for (int et = 0; et < 4; ++et)
            for (int rt = 0; rt < 4; ++rt) {
                uint2 pk;
                pk.x = pkh(acc[et][rt][0] * scale, acc[et][rt][1] * scale);
                pk.y = pkh(acc[et][rt][2] * scale, acc[et][rt][3] * scale);
                *(uint2*)&sm.oqk[l4 * 1160 + (wv * 4 + rt) * 72 + et * 16 + quad * 4] = pk;
            }
        __syncthreads();
        // lane-linear readout: wave store = 1KB contiguous
        for (int k = 0; k < 8; ++k) {
            int g = k * 256 + t; int h = g >> 7, rem = g & 127;
            int sl = rem >> 3, dq = (rem & 7) * 8;
            uint4 v = *(const uint4*)&sm.oqk[h * 1160 + sl * 72 + dq];
            *(uint4*)(Out + (((size_t)(n * HEADS + h) * SQ) + s0 + sl) * HD + dq) = v;
        }
    }
}

// ---------------------------------------------------------------------------
// Per-wave private staging of this wave's 16-key stripe of one 64-key tile.
// (r8, unchanged)
// ---------------------------------------------------------------------------
__device__ __forceinline__ void stage_stripe(const USH* __restrict__ Kg,
                                             const USH* __restrict__ Vg,
                                             int kt, USH* wbuf,
                                             int w, int lane)
{
#pragma unroll
    for (int j = 0; j < 2; ++j) {   // K: chunk = (lane>>4)+j*4, key = lane&15
        int chunk = (lane >> 4) + j * 4;
        glds16(Kg + (size_t)(kt * 64 + w * 16 + (lane & 15)) * HD + chunk * 8,
               wbuf + j * 512);
    }
#pragma unroll
    for (int j = 0; j < 2; ++j) {   // V: d = ((lane>>5)+j*2)*16 + ((lane&31)>>1)
        int d = ((lane >> 5) + j * 2) * 16 + ((lane & 31) >> 1);
        glds16(Vg + (size_t)d * SQ + kt * 64 + w * 16 + (lane & 1) * 8,
               wbuf + 1024 + j * 512);
    }
}

// ---------------------------------------------------------------------------
// Flash attention, no-max exp2 softmax. BARRIER-FREE main loop via PRIVATE
// per-wave staging (r8-verified 65.5us; r9 re-measure 73.7us on identical
// code calibrates cross-run noise at ~+/-10%). UNCHANGED in r10.
// ---------------------------------------------------------------------------
__global__ __launch_bounds__(256, 3) void attn_kernel(
    const USH* __restrict__ Qh, const USH* __restrict__ Kh,
    const USH* __restrict__ Vt, USH* __restrict__ Oh)
{
    __shared__ union {
        USH wbuf[4][3][2048];                                // 48 KB
        struct { float Osum[64][68]; float Lsum[64]; } r;    // 17.7 KB
    } lds;

    int t = threadIdx.x, w = t >> 6, lane = t & 63;
    int l4 = lane & 15, quad = lane >> 4;
    int b = blockIdx.x;
    int nh = b & 31;                 // all q-tiles of a head land on one XCD
    int q0 = (b >> 5) * 64;
    const USH* Qg = Qh + ((size_t)nh * SQ + q0) * HD;
    const USH* Kg = Kh + (size_t)nh * SQ * HD;
    const USH* Vg = Vt + (size_t)nh * HD * SQ;

    // Q fragments direct from global (one-time; B-operand layout)
    h8 bq[4][2];
#pragma unroll
    for (int qt = 0; qt < 4; ++qt)
#pragma unroll
        for (int ks = 0; ks < 2; ++ks)
            bq[qt][ks] = *(const h8*)(Qg + (size_t)(qt * 16 + l4) * HD + ks * 32 + quad * 8);

    f4 o[4][4];
#pragma unroll
    for (int dt = 0; dt < 4; ++dt)
#pragma unroll
        for (int qt = 0; qt < 4; ++qt) o[dt][qt] = (f4)(0.0f);
    float lsum[4] = {0.f, 0.f, 0.f, 0.f};

    // Private-region frag offsets (USH units).
    int koff = quad * 128 + l4 * 8;
    int voff = 1024 + l4 * 16 + quad * 4;

    // prologue: stage tiles 0,1 into bufs 0,1 (8 glds outstanding)
    stage_stripe(Kg, Vg, 0, lds.wbuf[w][0], w, lane);
    stage_stripe(Kg, Vg, 1, lds.wbuf[w][1], w, lane);

    for (int i = 0; i < 16; ++i) {
        int tA = 2 * i, tB = 2 * i + 1;
        USH* bufA = lds.wbuf[w][tA % 3];
        USH* bufB = lds.wbuf[w][tB % 3];

        // this wave's own DMA queue drained: tiles tA,tB resident
        asm volatile("s_waitcnt vmcnt(0)" ::: "memory");
        __builtin_amdgcn_sched_barrier(0);

        // read ALL fragments for the pair into regs (linear, conflict-free)
        h8 akA0 = *(const h8*)(bufA + koff);
        h8 akA1 = *(const h8*)(bufA + 512 + koff);
        h8 akB0 = *(const h8*)(bufB + koff);
        h8 akB1 = *(const h8*)(bufB + 512 + koff);
        h8 av8[4];
#pragma unroll
        for (int dt = 0; dt < 4; ++dt) {
            uint2 lo = *(const uint2*)(bufA + voff + dt * 256);
            uint2 hi = *(const uint2*)(bufB + voff + dt * 256);
            uint4 u; u.x = lo.x; u.y = lo.y; u.z = hi.x; u.w = hi.y;
            av8[dt] = __builtin_bit_cast(h8, u);
        }
        // frag reads complete -> safe to overwrite bufs with next pair's DMA
        asm volatile("s_waitcnt lgkmcnt(0)" ::: "memory");
        __builtin_amdgcn_sched_barrier(0);
        if (i < 15) {
            stage_stripe(Kg, Vg, tA + 2, lds.wbuf[w][(tA + 2) % 3], w, lane);
            stage_stripe(Kg, Vg, tB + 2, lds.wbuf[w][(tB + 2) % 3], w, lane);
        }

        // QK tile A -> pA (all qt; pA persists through PV)
        uint2 pA[4];
#pragma unroll
        for (int qt = 0; qt < 4; ++qt) {
            f4 s0 = __builtin_amdgcn_mfma_f32_16x16x32_f16(akA0, bq[qt][0], (f4)(0.0f), 0, 0, 0);
            f4 sc = __builtin_amdgcn_mfma_f32_16x16x32_f16(akA1, bq[qt][1], s0, 0, 0, 0);
            float p0 = __builtin_amdgcn_exp2f(sc[0]);
            float p1 = __builtin_amdgcn_exp2f(sc[1]);
            float p2 = __builtin_amdgcn_exp2f(sc[2]);
            float p3 = __builtin_amdgcn_exp2f(sc[3]);
            lsum[qt] += (p0 + p1) + (p2 + p3);
            pA[qt].x = pkh(p0, p1); pA[qt].y = pkh(p2, p3);
        }

        // QK tile B per qt -> pB transient -> one K=32 PV over {tA,tB}
#pragma unroll
        for (int qt = 0; qt < 4; ++qt) {
            f4 s0 = __builtin_amdgcn_mfma_f32_16x16x32_f16(akB0, bq[qt][0], (f4)(0.0f), 0, 0, 0);
            f4 sc = __builtin_amdgcn_mfma_f32_16x16x32_f16(akB1, bq[qt][1], s0, 0, 0, 0);
            float p0 = __builtin_amdgcn_exp2f(sc[0]);
            float p1 = __builtin_amdgcn_exp2f(sc[1]);
            float p2 = __builtin_amdgcn_exp2f(sc[2]);
            float p3 = __builtin_amdgcn_exp2f(sc[3]);
            lsum[qt] += (p0 + p1) + (p2 + p3);
            uint4 u;
            u.x = pA[qt].x; u.y = pA[qt].y;
            u.z = pkh(p0, p1); u.w = pkh(p2, p3);
            h8 pp = __builtin_bit_cast(h8, u);
#pragma unroll
            for (int dt = 0; dt < 4; ++dt)
                o[dt][qt] = __builtin_amdgcn_mfma_f32_16x16x32_f16(
                    av8[dt], pp, o[dt][qt], 0, 0, 0);
        }
    }

    // quad-reduce lsum (quads hold disjoint keys of this wave's stripe)
#pragma unroll
    for (int qt = 0; qt < 4; ++qt) {
        lsum[qt] += __shfl_xor(lsum[qt], 16, 64);
        lsum[qt] += __shfl_xor(lsum[qt], 32, 64);
    }

    // cross-wave O/L reduction through LDS (union reuse)
    __syncthreads();
    for (int ph = 0; ph < 4; ++ph) {
        if (w == ph) {
            for (int dt = 0; dt < 4; ++dt)
                for (int qt = 0; qt < 4; ++qt) {
                    float* dst = &lds.r.Osum[qt * 16 + l4][dt * 16 + quad * 4];
                    f4 val = o[dt][qt];
                    if (ph) val += *(const f4*)dst;
                    *(f4*)dst = val;
                }
            if (quad == 0)
                for (int qt = 0; qt < 4; ++qt) {
                    int qi = qt * 16 + l4;
                    lds.r.Lsum[qi] = ph ? (lds.r.Lsum[qi] + lsum[qt]) : lsum[qt];
                }
        }
        __syncthreads();
    }

    // epilogue: normalize + f16 store
    int n = nh >> 4, h = nh & 15;
    int q = t >> 2, d0 = (t & 3) * 16;
    float inv = 1.0f / lds.r.Lsum[q];
    float vv[16];
#pragma unroll
    for (int i = 0; i < 4; ++i) {
        f4 x = *(const f4*)&lds.r.Osum[q][d0 + i * 4];
        vv[i * 4 + 0] = x[0] * inv; vv[i * 4 + 1] = x[1] * inv;
        vv[i * 4 + 2] = x[2] * inv; vv[i * 4 + 3] = x[3] * inv;
    }
    uint4 ou0, ou1;
    ou0.x = pkh(vv[0], vv[1]);   ou0.y = pkh(vv[2], vv[3]);
    ou0.z = pkh(vv[4], vv[5]);   ou0.w = pkh(vv[6], vv[7]);
    ou1.x = pkh(vv[8], vv[9]);   ou1.y = pkh(vv[10], vv[11]);
    ou1.z = pkh(vv[12], vv[13]); ou1.w = pkh(vv[14], vv[15]);
    USH* ob = Oh + ((size_t)(n * SQ + q0 + q)) * EMB + h * HD + d0;
    *(uint4*)ob = ou0;
    *(uint4*)(ob + 8) = ou1;
}

// ---------------------------------------------------------------------------
// Output GEMM: C[4096][1024] = A[4096][1024] * B[1024][1024]^T (f16 -> fp32)
// BM=128, BN=64, BK=64 dbuf (48KB), grid 512 = 2 blocks/CU (r9-verified).
// r10 CHANGE: coalesced C epilogue. The old store wrote 4B/lane at
// [row=quad*4+r][col=l4] -- a wave instr = 4 rows x 64B segments, 16MB of
// fp32 at 64B granule. Now acc bounces through LDS (union reuse of the
// dead Al/Bl staging; float Ct[128][66], +2 pad -> write phases hit all
// 32 banks, read phases 2-way=free) and goes out lane-linear: 16 lanes =
// one 256B row segment, uint4 stores, 4x fewer store instructions.
// Same medicine as proj's r9 fix.
// ---------------------------------------------------------------------------
__global__ __launch_bounds__(256, 2) void gemm_bt(const USH* __restrict__ A,
                                                  const USH* __restrict__ B,
                                                  float* __restrict__ C)
{
    __shared__ __align__(16) union {
        struct { USH Al[2][8192]; USH Bl[2][4096]; } s;   // 48 KB
        float Ct[128][66];                                 // 33.8 KB
    } sm;
    int t = threadIdx.x, w = t >> 6, lane = t & 63;
    int l4 = lane & 15, quad = lane >> 4;
    int b = blockIdx.x;
    int m0 = (b & 31) * 128;
    int n0 = (b >> 5) * 64;
    int wm = (w >> 1) * 64, wn = (w & 1) * 32;

    f4 acc[4][2];
    for (int mt = 0; mt < 4; ++mt)
        for (int nt = 0; nt < 2; ++nt) acc[mt][nt] = (f4)(0.0f);

    int aslot[4][2], bslot[2][2];
#pragma unroll
    for (int mt = 0; mt < 4; ++mt)
#pragma unroll
        for (int ks = 0; ks < 2; ++ks) {
            int m = wm + mt * 16 + l4;
            aslot[mt][ks] = m * 8 + ((ks * 4 + quad) ^ (m & 7));
        }
#pragma unroll
    for (int nt = 0; nt < 2; ++nt)
#pragma unroll
        for (int ks = 0; ks < 2; ++ks) {
            int nn = wn + nt * 16 + l4;
            bslot[nt][ks] = nn * 8 + ((ks * 4 + quad) ^ (nn & 7));
        }

    // prologue: stage ki=0 into buffer 0
#pragma unroll
    for (int j = 0; j < 4; ++j) {
        int s = (w * 4 + j) * 64 + lane;          // 0..1023
        int r = s >> 3, c = (s & 7) ^ (r & 7);    // r 0..127
        glds16(A + (size_t)(m0 + r) * 1024 + c * 8, sm.s.Al[0] + s * 8);
    }
#pragma unroll
    for (int j = 0; j < 2; ++j) {
        int s = (w * 2 + j) * 64 + lane;          // 0..511
        int r = s >> 3, c = (s & 7) ^ (r & 7);    // r 0..63
        glds16(B + (size_t)(n0 + r) * 1024 + c * 8, sm.s.Bl[0] + s * 8);
    }

    for (int ki = 0; ki < 16; ++ki) {
        int cur = ki & 1;
        __syncthreads();
        if (ki + 1 < 16) {
            int k0 = (ki + 1) * 64;
#pragma unroll
            for (int j = 0; j < 4; ++j) {
                int s = (w * 4 + j) * 64 + lane;
                int r = s >> 3, c = (s & 7) ^ (r & 7);
                glds16(A + (size_t)(m0 + r) * 1024 + k0 + c * 8, sm.s.Al[cur ^ 1] + s * 8);
            }
#pragma unroll
            for (int j = 0; j < 2; ++j) {
                int s = (w * 2 + j) * 64 + lane;
                int r = s >> 3, c = (s & 7) ^ (r & 7);
                glds16(B + (size_t)(n0 + r) * 1024 + k0 + c * 8, sm.s.Bl[cur ^ 1] + s * 8);
            }
        }

        h8 a[4][2], bf[2][2];
#pragma unroll
        for (int mt = 0; mt < 4; ++mt)
#pragma unroll
            for (int ks = 0; ks < 2; ++ks)
                a[mt][ks] = *(const h8*)(sm.s.Al[cur] + aslot[mt][ks] * 8);
#pragma unroll
        for (int nt = 0; nt < 2; ++nt)
#pragma unroll
            for (int ks = 0; ks < 2; ++ks)
                bf[nt][ks] = *(const h8*)(sm.s.Bl[cur] + bslot[nt][ks] * 8);
#pragma unroll
        for (int mt = 0; mt < 4; ++mt)
#pragma unroll
            for (int nt = 0; nt < 2; ++nt)
#pragma unroll
                for (int ks = 0; ks < 2; ++ks)
                    acc[mt][nt] = __builtin_amdgcn_mfma_f32_16x16x32_f16(
                        a[mt][ks], bf[nt][ks], acc[mt][nt], 0, 0, 0);
    }

    // ---- coalesced epilogue: acc -> LDS -> 256B-segment uint4 stores ----
    __syncthreads();   // all waves done with Al/Bl before union overwrite
#pragma unroll
    for (int mt = 0; mt < 4; ++mt)
#pragma unroll
        for (int nt = 0; nt < 2; ++nt)
#pragma unroll
            for (int r = 0; r < 4; ++r)
                sm.Ct[wm + mt * 16 + quad * 4 + r][wn + nt * 16 + l4] = acc[mt][nt][r];
    __syncthreads();
    // 128 rows x 64 f32 = 32KB; thread covers 16B x 8: row = g>>4, colq = (g&15)*4
#pragma unroll
    for (int k = 0; k < 8; ++k) {
        int g = k * 256 + t;
        int row = g >> 4, colq = (g & 15) * 4;
        f4 v = *(const f4*)&sm.Ct[row][colq];
        *(f4*)&C[(size_t)(m0 + row) * 1024 + n0 + colq] = v;
    }
}

// ---------------------------------------------------------------------------
extern "C" void kernel_launch(void* const* d_in, const int* in_sizes, int n_in,
                              void* d_out, int out_size, void* d_ws, size_t ws_size,
                              hipStream_t stream) {
    const float* k_in = (const float*)d_in[0];
    const float* q_in = (const float*)d_in[1];
    const float* v_in = (const float*)d_in[2];
    const float* Wk   = (const float*)d_in[3];
    const float* Wq   = (const float*)d_in[4];
    const float* Wv   = (const float*)d_in[5];
    const float* Wo   = (const float*)d_in[6];
    float* out = (float*)d_out;

    char* ws = (char*)d_ws;
    USH* Qh  = (USH*)(ws);               //  8 MB [n,h,s,d] f16 (scale folded)
    USH* Kh  = (USH*)(ws + 8388608);     //  8 MB [n,h,s,d]
    USH* Vt  = (USH*)(ws + 16777216);    //  8 MB [n,h,d,s]
    USH* Oh  = (USH*)(ws + 25165824);    //  8 MB [n,s,1024]
    USH* Wob = (USH*)(ws + 33554432);    //  2 MB

    proj_fused<<<dim3(256, 4), dim3(256), 0, stream>>>(
        q_in, k_in, v_in, Wq, Wk, Wv, Wo, Qh, Kh, Vt, Wob);
    attn_kernel<<<dim3(1024), dim3(256), 0, stream>>>(Qh, Kh, Vt, Oh);
    gemm_bt<<<dim3(512), dim3(256), 0, stream>>>(Oh, Wob, out);
}

// Round 11
// 167.286 us; speedup vs baseline: 1.0653x; 1.0653x over previous
//
#include <hip/hip_runtime.h>

#define SQ   2048
#define HEADS 16
#define HD   64
#define EMB  1024

typedef __attribute__((ext_vector_type(2))) __fp16 h2;
typedef __attribute__((ext_vector_type(4))) __fp16 h4;
typedef __attribute__((ext_vector_type(8))) __fp16 h8;
typedef __attribute__((ext_vector_type(4))) float f4;
typedef unsigned short USH;
typedef unsigned int   UI;

__device__ __forceinline__ UI pkh(float a, float b) {   // pack 2 f16 (RTZ)
    h2 v = __builtin_amdgcn_cvt_pkrtz(a, b);
    return __builtin_bit_cast(UI, v);
}

// async global->LDS, 16B per lane; LDS dest = wave-uniform base + lane*16
__device__ __forceinline__ void glds16(const void* g, void* l) {
    __builtin_amdgcn_global_load_lds(
        (const __attribute__((address_space(1))) unsigned int*)g,
        (__attribute__((address_space(3))) unsigned int*)l, 16, 0, 0);
}

// ---------------------------------------------------------------------------
// Fused Q/K/V per-head projections (y=0,1,2) + Wo fp32->f16 cast (y=3).
// C = W * X^T (operand swap). Q/K written [n,h,s,d]. Q carries
// 0.125*log2(e) so attention softmax is a bare exp2.
// r11 CHANGE: Vt layout is now SLAB-TILED [n,h][kt(32)][g(4)][d(64)][k16(16)]
// (slab = 16 consecutive tokens x all 64 d = 2KB contiguous). Old [h][d][s]
// made attn's stage_v read 8B/lane from 4KB-strided rows -- every 64B L2
// sector delivered 32B (2x V over-fetch; V was +50% of staged traffic).
// A proj block covers exactly one (kt,g) slab (16 tokens), so its writeout
// becomes 64d x 32B = 2KB contiguous runs (was 32B at 16KB stride).
// attn's LDS image is byte-identical (verified: old scattered stage wrote
// linear [d][k16]; new stage is an identity copy of the same bytes).
// ---------------------------------------------------------------------------
__global__ __launch_bounds__(256) void proj_fused(
    const float* __restrict__ q_in, const float* __restrict__ k_in,
    const float* __restrict__ v_in, const float* __restrict__ Wq,
    const float* __restrict__ Wk,   const float* __restrict__ Wv,
    const float* __restrict__ Wo,
    USH* __restrict__ Qh, USH* __restrict__ Kh, USH* __restrict__ Vt,
    USH* __restrict__ Wob)
{
    int t = threadIdx.x;
    if (blockIdx.y == 3) {
        int i = blockIdx.x * 256 + t;
        for (int j = 0; j < 4; ++j) {
            float4 v = ((const float4*)Wo)[i + j * 65536];
            uint2 pk; pk.x = pkh(v.x, v.y); pk.y = pkh(v.z, v.w);
            *(uint2*)(Wob + ((size_t)i + (size_t)j * 65536) * 4) = pk;
        }
        return;
    }
    const float* X = (blockIdx.y == 0) ? q_in : (blockIdx.y == 1) ? k_in : v_in;
    const float* W = (blockIdx.y == 0) ? Wq   : (blockIdx.y == 1) ? Wk   : Wv;
    float scale    = (blockIdx.y == 0) ? 0.18033688011112043f : 1.0f;

    int bx = (blockIdx.x & 7) * 32 + (blockIdx.x >> 3);

    __shared__ __align__(16) union {
        struct { USH Xl[256][72]; USH Wl[64][72]; } in;   // 46080 B
        USH oqk[16 * 1160];                               // [h][sl(72)][d] 37120 B
        USH ov[16 * 1544];                                // [h][d(24)][sl] 49408 B
    } sm;

    const float4* Xg = (const float4*)(X + (size_t)bx * 16384);
    for (int j = 0; j < 16; ++j) {
        int f = t + j * 256;
        float4 v = Xg[f];
        int row = f >> 4; int col = (f & 15) << 2;
        uint2 pk; pk.x = pkh(v.x, v.y); pk.y = pkh(v.z, v.w);
        *(uint2*)&sm.in.Xl[row][col] = pk;
    }
    const float4* Wg = (const float4*)W;
    for (int j = 0; j < 4; ++j) {
        int f = t + j * 256;
        float4 v = Wg[f];
        int row = f >> 4; int col = (f & 15) << 2;
        uint2 pk; pk.x = pkh(v.x, v.y); pk.y = pkh(v.z, v.w);
        *(uint2*)&sm.in.Wl[row][col] = pk;
    }
    __syncthreads();

    int wv = t >> 6, lane = t & 63, l4 = lane & 15, quad = lane >> 4;

    h8 wf[4][2], xf[4][2];
    for (int et = 0; et < 4; ++et)
        for (int ks = 0; ks < 2; ++ks)
            wf[et][ks] = *(const h8*)&sm.in.Wl[et * 16 + l4][ks * 32 + quad * 8];
    for (int rt = 0; rt < 4; ++rt)
        for (int ks = 0; ks < 2; ++ks)
            xf[rt][ks] = *(const h8*)&sm.in.Xl[wv * 64 + rt * 16 + l4][ks * 32 + quad * 8];

    __syncthreads();   // all waves done reading sm.in before union reuse

    f4 acc[4][4];
    for (int et = 0; et < 4; ++et)
        for (int rt = 0; rt < 4; ++rt) acc[et][rt] = (f4)(0.0f);
    for (int et = 0; et < 4; ++et)
        for (int rt = 0; rt < 4; ++rt)
            for (int ks = 0; ks < 2; ++ks)
                acc[et][rt] = __builtin_amdgcn_mfma_f32_16x16x32_f16(
                    wf[et][ks], xf[rt][ks], acc[et][rt], 0, 0, 0);

    int ns0 = bx * 16;
    int n = ns0 >> 11, s0 = ns0 & 2047;   // block never crosses n (2048%16==0)

    if (blockIdx.y == 2) {
        // LDS layout [h][d][sl]: h-stride 1544, d-stride 24 (48B, 16B-aligned)
        for (int et = 0; et < 4; ++et)
            for (int j = 0; j < 4; ++j) {
                int e = et * 16 + quad * 4 + j;
                uint2 pk;
                pk.x = pkh(acc[et][0][j], acc[et][1][j]);
                pk.y = pkh(acc[et][2][j], acc[et][3][j]);
                *(uint2*)&sm.ov[l4 * 1544 + e * 24 + wv * 4] = pk;
            }
        __syncthreads();
        // slab-tiled writeout: per (h,d) 32B at [h][slab = s0>>4][d][k16],
        // consecutive d -> consecutive 32B -> 2KB contiguous runs per (h)
        for (int k = 0; k < 4; ++k) {
            int g = k * 256 + t; int h = g >> 6, d = g & 63;
            const USH* src = &sm.ov[h * 1544 + d * 24];
            uint4 v0 = *(const uint4*)src;
            uint4 v1 = *(const uint4*)(src + 8);
            USH* dst = Vt + ((size_t)(n * HEADS + h) * HD * SQ) + (s0 >> 4) * 1024 + d * 16;
            *(uint4*)dst = v0;
            *(uint4*)(dst + 8) = v1;
        }
    } else {
        USH* Out = (blockIdx.y == 0) ? Qh : Kh;
        // LDS layout [h][sl][d]: h-stride 1160, sl-stride 72 (144B, 16B-aligned)
        for (int et = 0; et < 4; ++et)
            for (int rt = 0; rt < 4; ++rt) {
                uint2 pk;
                pk.x = pkh(acc[et][rt][0] * scale, acc[et][rt][1] * scale);
                pk.y = pkh(acc[et][rt][2] * scale, acc[et][rt][3] * scale);
                *(uint2*)&sm.oqk[l4 * 1160 + (wv * 4 + rt) * 72 + et * 16 + quad * 4] = pk;
            }
        __syncthreads();
        // lane-linear readout: wave store = 1KB contiguous
        for (int k = 0; k < 8; ++k) {
            int g = k * 256 + t; int h = g >> 7, rem = g & 127;
            int sl = rem >> 3, dq = (rem & 7) * 8;
            uint4 v = *(const uint4*)&sm.oqk[h * 1160 + sl * 72 + dq];
            *(uint4*)(Out + (((size_t)(n * HEADS + h) * SQ) + s0 + sl) * HD + dq) = v;
        }
    }
}

// ---------------------------------------------------------------------------
// Per-wave private staging of this wave's 16-key stripe of one 64-key tile.
// K: 2 glds, full 128B rows (sector-efficient already; LDS layout
// [chunk][key] is the r8-verified 2-way-free pattern).
// V (r11): Vt is slab-tiled, so the stripe is ONE 2KB contiguous run --
// 2 glds of 1KB sequential (was 8B/lane from 4KB-strided rows = 2x sector
// over-fetch). LDS image [d][k16] is byte-identical to r8's.
// ---------------------------------------------------------------------------
__device__ __forceinline__ void stage_stripe(const USH* __restrict__ Kg,
                                             const USH* __restrict__ Vg,
                                             int kt, USH* wbuf,
                                             int w, int lane)
{
#pragma unroll
    for (int j = 0; j < 2; ++j) {   // K: chunk = (lane>>4)+j*4, key = lane&15
        int chunk = (lane >> 4) + j * 4;
        glds16(Kg + (size_t)(kt * 64 + w * 16 + (lane & 15)) * HD + chunk * 8,
               wbuf + j * 512);
    }
#pragma unroll
    for (int j = 0; j < 2; ++j) {   // V: contiguous slab copy
        glds16(Vg + (size_t)(kt * 4 + w) * 1024 + j * 512 + lane * 8,
               wbuf + 1024 + j * 512);
    }
}

// ---------------------------------------------------------------------------
// Flash attention, no-max exp2 softmax. BARRIER-FREE main loop via PRIVATE
// per-wave staging (r8-verified 65.5us; r10 re-confirm 65.7us). r11: code
// identical except stage_stripe's V source addressing (slab-tiled Vt).
// This is the clean test of the last unexplained invariant: ~7.8 TB/s
// aggregate glds staging rate across six schedules (23% of L2 ceiling).
// V's 2x sector over-fetch was +50% of staged traffic; if the invariant is
// a sector/BW ceiling this is -15-20%; if a latency floor, it's null and
// the pipeline is at its practical floor (pre-committed).
// ---------------------------------------------------------------------------
__global__ __launch_bounds__(256, 3) void attn_kernel(
    const USH* __restrict__ Qh, const USH* __restrict__ Kh,
    const USH* __restrict__ Vt, USH* __restrict__ Oh)
{
    __shared__ union {
        USH wbuf[4][3][2048];                                // 48 KB
        struct { float Osum[64][68]; float Lsum[64]; } r;    // 17.7 KB
    } lds;

    int t = threadIdx.x, w = t >> 6, lane = t & 63;
    int l4 = lane & 15, quad = lane >> 4;
    int b = blockIdx.x;
    int nh = b & 31;                 // all q-tiles of a head land on one XCD
    int q0 = (b >> 5) * 64;
    const USH* Qg = Qh + ((size_t)nh * SQ + q0) * HD;
    const USH* Kg = Kh + (size_t)nh * SQ * HD;
    const USH* Vg = Vt + (size_t)nh * HD * SQ;

    // Q fragments direct from global (one-time; B-operand layout)
    h8 bq[4][2];
#pragma unroll
    for (int qt = 0; qt < 4; ++qt)
#pragma unroll
        for (int ks = 0; ks < 2; ++ks)
            bq[qt][ks] = *(const h8*)(Qg + (size_t)(qt * 16 + l4) * HD + ks * 32 + quad * 8);

    f4 o[4][4];
#pragma unroll
    for (int dt = 0; dt < 4; ++dt)
#pragma unroll
        for (int qt = 0; qt < 4; ++qt) o[dt][qt] = (f4)(0.0f);
    float lsum[4] = {0.f, 0.f, 0.f, 0.f};

    // Private-region frag offsets (USH units).
    int koff = quad * 128 + l4 * 8;
    int voff = 1024 + l4 * 16 + quad * 4;

    // prologue: stage tiles 0,1 into bufs 0,1 (8 glds outstanding)
    stage_stripe(Kg, Vg, 0, lds.wbuf[w][0], w, lane);
    stage_stripe(Kg, Vg, 1, lds.wbuf[w][1], w, lane);

    for (int i = 0; i < 16; ++i) {
        int tA = 2 * i, tB = 2 * i + 1;
        USH* bufA = lds.wbuf[w][tA % 3];
        USH* bufB = lds.wbuf[w][tB % 3];

        // this wave's own DMA queue drained: tiles tA,tB resident
        asm volatile("s_waitcnt vmcnt(0)" ::: "memory");
        __builtin_amdgcn_sched_barrier(0);

        // read ALL fragments for the pair into regs (linear, conflict-free)
        h8 akA0 = *(const h8*)(bufA + koff);
        h8 akA1 = *(const h8*)(bufA + 512 + koff);
        h8 akB0 = *(const h8*)(bufB + koff);
        h8 akB1 = *(const h8*)(bufB + 512 + koff);
        h8 av8[4];
#pragma unroll
        for (int dt = 0; dt < 4; ++dt) {
            uint2 lo = *(const uint2*)(bufA + voff + dt * 256);
            uint2 hi = *(const uint2*)(bufB + voff + dt * 256);
            uint4 u; u.x = lo.x; u.y = lo.y; u.z = hi.x; u.w = hi.y;
            av8[dt] = __builtin_bit_cast(h8, u);
        }
        // frag reads complete -> safe to overwrite bufs with next pair's DMA
        asm volatile("s_waitcnt lgkmcnt(0)" ::: "memory");
        __builtin_amdgcn_sched_barrier(0);
        if (i < 15) {
            stage_stripe(Kg, Vg, tA + 2, lds.wbuf[w][(tA + 2) % 3], w, lane);
            stage_stripe(Kg, Vg, tB + 2, lds.wbuf[w][(tB + 2) % 3], w, lane);
        }

        // QK tile A -> pA (all qt; pA persists through PV)
        uint2 pA[4];
#pragma unroll
        for (int qt = 0; qt < 4; ++qt) {
            f4 s0 = __builtin_amdgcn_mfma_f32_16x16x32_f16(akA0, bq[qt][0], (f4)(0.0f), 0, 0, 0);
            f4 sc = __builtin_amdgcn_mfma_f32_16x16x32_f16(akA1, bq[qt][1], s0, 0, 0, 0);
            float p0 = __builtin_amdgcn_exp2f(sc[0]);
            float p1 = __builtin_amdgcn_exp2f(sc[1]);
            float p2 = __builtin_amdgcn_exp2f(sc[2]);
            float p3 = __builtin_amdgcn_exp2f(sc[3]);
            lsum[qt] += (p0 + p1) + (p2 + p3);
            pA[qt].x = pkh(p0, p1); pA[qt].y = pkh(p2, p3);
        }

        // QK tile B per qt -> pB transient -> one K=32 PV over {tA,tB}
#pragma unroll
        for (int qt = 0; qt < 4; ++qt) {
            f4 s0 = __builtin_amdgcn_mfma_f32_16x16x32_f16(akB0, bq[qt][0], (f4)(0.0f), 0, 0, 0);
            f4 sc = __builtin_amdgcn_mfma_f32_16x16x32_f16(akB1, bq[qt][1], s0, 0, 0, 0);
            float p0 = __builtin_amdgcn_exp2f(sc[0]);
            float p1 = __builtin_amdgcn_exp2f(sc[1]);
            float p2 = __builtin_amdgcn_exp2f(sc[2]);
            float p3 = __builtin_amdgcn_exp2f(sc[3]);
            lsum[qt] += (p0 + p1) + (p2 + p3);
            uint4 u;
            u.x = pA[qt].x; u.y = pA[qt].y;
            u.z = pkh(p0, p1); u.w = pkh(p2, p3);
            h8 pp = __builtin_bit_cast(h8, u);
#pragma unroll
            for (int dt = 0; dt < 4; ++dt)
                o[dt][qt] = __builtin_amdgcn_mfma_f32_16x16x32_f16(
                    av8[dt], pp, o[dt][qt], 0, 0, 0);
        }
    }

    // quad-reduce lsum (quads hold disjoint keys of this wave's stripe)
#pragma unroll
    for (int qt = 0; qt < 4; ++qt) {
        lsum[qt] += __shfl_xor(lsum[qt], 16, 64);
        lsum[qt] += __shfl_xor(lsum[qt], 32, 64);
    }

    // cross-wave O/L reduction through LDS (union reuse)
    __syncthreads();
    for (int ph = 0; ph < 4; ++ph) {
        if (w == ph) {
            for (int dt = 0; dt < 4; ++dt)
                for (int qt = 0; qt < 4; ++qt) {
                    float* dst = &lds.r.Osum[qt * 16 + l4][dt * 16 + quad * 4];
                    f4 val = o[dt][qt];
                    if (ph) val += *(const f4*)dst;
                    *(f4*)dst = val;
                }
            if (quad == 0)
                for (int qt = 0; qt < 4; ++qt) {
                    int qi = qt * 16 + l4;
                    lds.r.Lsum[qi] = ph ? (lds.r.Lsum[qi] + lsum[qt]) : lsum[qt];
                }
        }
        __syncthreads();
    }

    // epilogue: normalize + f16 store
    int n = nh >> 4, h = nh & 15;
    int q = t >> 2, d0 = (t & 3) * 16;
    float inv = 1.0f / lds.r.Lsum[q];
    float vv[16];
#pragma unroll
    for (int i = 0; i < 4; ++i) {
        f4 x = *(const f4*)&lds.r.Osum[q][d0 + i * 4];
        vv[i * 4 + 0] = x[0] * inv; vv[i * 4 + 1] = x[1] * inv;
        vv[i * 4 + 2] = x[2] * inv; vv[i * 4 + 3] = x[3] * inv;
    }
    uint4 ou0, ou1;
    ou0.x = pkh(vv[0], vv[1]);   ou0.y = pkh(vv[2], vv[3]);
    ou0.z = pkh(vv[4], vv[5]);   ou0.w = pkh(vv[6], vv[7]);
    ou1.x = pkh(vv[8], vv[9]);   ou1.y = pkh(vv[10], vv[11]);
    ou1.z = pkh(vv[12], vv[13]); ou1.w = pkh(vv[14], vv[15]);
    USH* ob = Oh + ((size_t)(n * SQ + q0 + q)) * EMB + h * HD + d0;
    *(uint4*)ob = ou0;
    *(uint4*)(ob + 8) = ou1;
}

// ---------------------------------------------------------------------------
// Output GEMM: C[4096][1024] = A[4096][1024] * B[1024][1024]^T (f16 -> fp32)
// BM=128, BN=64, BK=64 dbuf (48KB), grid 512 = 2 blocks/CU; coalesced LDS
// C epilogue (r10 -- neutral but kept: fewer store instrs, no downside).
// ---------------------------------------------------------------------------
__global__ __launch_bounds__(256, 2) void gemm_bt(const USH* __restrict__ A,
                                                  const USH* __restrict__ B,
                                                  float* __restrict__ C)
{
    __shared__ __align__(16) union {
        struct { USH Al[2][8192]; USH Bl[2][4096]; } s;   // 48 KB
        float Ct[128][66];                                 // 33.8 KB
    } sm;
    int t = threadIdx.x, w = t >> 6, lane = t & 63;
    int l4 = lane & 15, quad = lane >> 4;
    int b = blockIdx.x;
    int m0 = (b & 31) * 128;
    int n0 = (b >> 5) * 64;
    int wm = (w >> 1) * 64, wn = (w & 1) * 32;

    f4 acc[4][2];
    for (int mt = 0; mt < 4; ++mt)
        for (int nt = 0; nt < 2; ++nt) acc[mt][nt] = (f4)(0.0f);

    int aslot[4][2], bslot[2][2];
#pragma unroll
    for (int mt = 0; mt < 4; ++mt)
#pragma unroll
        for (int ks = 0; ks < 2; ++ks) {
            int m = wm + mt * 16 + l4;
            aslot[mt][ks] = m * 8 + ((ks * 4 + quad) ^ (m & 7));
        }
#pragma unroll
    for (int nt = 0; nt < 2; ++nt)
#pragma unroll
        for (int ks = 0; ks < 2; ++ks) {
            int nn = wn + nt * 16 + l4;
            bslot[nt][ks] = nn * 8 + ((ks * 4 + quad) ^ (nn & 7));
        }

    // prologue: stage ki=0 into buffer 0
#pragma unroll
    for (int j = 0; j < 4; ++j) {
        int s = (w * 4 + j) * 64 + lane;          // 0..1023
        int r = s >> 3, c = (s & 7) ^ (r & 7);    // r 0..127
        glds16(A + (size_t)(m0 + r) * 1024 + c * 8, sm.s.Al[0] + s * 8);
    }
#pragma unroll
    for (int j = 0; j < 2; ++j) {
        int s = (w * 2 + j) * 64 + lane;          // 0..511
        int r = s >> 3, c = (s & 7) ^ (r & 7);    // r 0..63
        glds16(B + (size_t)(n0 + r) * 1024 + c * 8, sm.s.Bl[0] + s * 8);
    }

    for (int ki = 0; ki < 16; ++ki) {
        int cur = ki & 1;
        __syncthreads();
        if (ki + 1 < 16) {
            int k0 = (ki + 1) * 64;
#pragma unroll
            for (int j = 0; j < 4; ++j) {
                int s = (w * 4 + j) * 64 + lane;
                int r = s >> 3, c = (s & 7) ^ (r & 7);
                glds16(A + (size_t)(m0 + r) * 1024 + k0 + c * 8, sm.s.Al[cur ^ 1] + s * 8);
            }
#pragma unroll
            for (int j = 0; j < 2; ++j) {
                int s = (w * 2 + j) * 64 + lane;
                int r = s >> 3, c = (s & 7) ^ (r & 7);
                glds16(B + (size_t)(n0 + r) * 1024 + k0 + c * 8, sm.s.Bl[cur ^ 1] + s * 8);
            }
        }

        h8 a[4][2], bf[2][2];
#pragma unroll
        for (int mt = 0; mt < 4; ++mt)
#pragma unroll
            for (int ks = 0; ks < 2; ++ks)
                a[mt][ks] = *(const h8*)(sm.s.Al[cur] + aslot[mt][ks] * 8);
#pragma unroll
        for (int nt = 0; nt < 2; ++nt)
#pragma unroll
            for (int ks = 0; ks < 2; ++ks)
                bf[nt][ks] = *(const h8*)(sm.s.Bl[cur] + bslot[nt][ks] * 8);
#pragma unroll
        for (int mt = 0; mt < 4; ++mt)
#pragma unroll
            for (int nt = 0; nt < 2; ++nt)
#pragma unroll
                for (int ks = 0; ks < 2; ++ks)
                    acc[mt][nt] = __builtin_amdgcn_mfma_f32_16x16x32_f16(
                        a[mt][ks], bf[nt][ks], acc[mt][nt], 0, 0, 0);
    }

    // ---- coalesced epilogue: acc -> LDS -> 256B-segment uint4 stores ----
    __syncthreads();   // all waves done with Al/Bl before union overwrite
#pragma unroll
    for (int mt = 0; mt < 4; ++mt)
#pragma unroll
        for (int nt = 0; nt < 2; ++nt)
#pragma unroll
            for (int r = 0; r < 4; ++r)
                sm.Ct[wm + mt * 16 + quad * 4 + r][wn + nt * 16 + l4] = acc[mt][nt][r];
    __syncthreads();
#pragma unroll
    for (int k = 0; k < 8; ++k) {
        int g = k * 256 + t;
        int row = g >> 4, colq = (g & 15) * 4;
        f4 v = *(const f4*)&sm.Ct[row][colq];
        *(f4*)&C[(size_t)(m0 + row) * 1024 + n0 + colq] = v;
    }
}

// ---------------------------------------------------------------------------
extern "C" void kernel_launch(void* const* d_in, const int* in_sizes, int n_in,
                              void* d_out, int out_size, void* d_ws, size_t ws_size,
                              hipStream_t stream) {
    const float* k_in = (const float*)d_in[0];
    const float* q_in = (const float*)d_in[1];
    const float* v_in = (const float*)d_in[2];
    const float* Wk   = (const float*)d_in[3];
    const float* Wq   = (const float*)d_in[4];
    const float* Wv   = (const float*)d_in[5];
    const float* Wo   = (const float*)d_in[6];
    float* out = (float*)d_out;

    char* ws = (char*)d_ws;
    USH* Qh  = (USH*)(ws);               //  8 MB [n,h,s,d] f16 (scale folded)
    USH* Kh  = (USH*)(ws + 8388608);     //  8 MB [n,h,s,d]
    USH* Vt  = (USH*)(ws + 16777216);    //  8 MB [n,h][kt][g][d][k16] slab-tiled
    USH* Oh  = (USH*)(ws + 25165824);    //  8 MB [n,s,1024]
    USH* Wob = (USH*)(ws + 33554432);    //  2 MB

    proj_fused<<<dim3(256, 4), dim3(256), 0, stream>>>(
        q_in, k_in, v_in, Wq, Wk, Wv, Wo, Qh, Kh, Vt, Wob);
    attn_kernel<<<dim3(1024), dim3(256), 0, stream>>>(Qh, Kh, Vt, Oh);
    gemm_bt<<<dim3(1024 / 2), dim3(256), 0, stream>>>(Oh, Wob, out);
}